// Round 2
// baseline (99.168 us; speedup 1.0000x reference)
//
#include <hip/hip_runtime.h>

#define BATCH 4
#define QDIM 1024
#define KDIM 1024
#define EDIM 512
#define H 32
#define VDIM 256
#define QT 8

#define TWO_LOG2E 2.8853900817779268f
#define LOG2E 1.4426950408889634f

// ---------------------------------------------------------------------------
// Kernel 1: Eq = exp2(2*log2e * (queries @ Wq)), Ek likewise for keys.
// 256 blocks (128 q + 128 k) x 512 threads; block = 32 rows x 16 h2-groups.
// ---------------------------------------------------------------------------
__global__ __launch_bounds__(512) void proj_kernel(
    const float* __restrict__ qin, const float* __restrict__ kin,
    const float* __restrict__ Wqm, const float* __restrict__ Wkm,
    float* __restrict__ qp, float* __restrict__ kp)
{
    const int tid = (int)threadIdx.x;
    const bool is_k = blockIdx.x >= 128;
    const float* in = is_k ? kin : qin;
    const float* W  = is_k ? Wkm : Wqm;
    float* outp     = is_k ? kp : qp;
    const int row = ((int)blockIdx.x & 127) * 32 + (tid >> 4);
    const int h2  = (tid & 15) * 2;

    const float* inrow = in + (size_t)row * EDIM;
    float a0 = 0.f, a1 = 0.f;

    for (int e = 0; e < EDIM; e += 4) {
        float4 a4 = *reinterpret_cast<const float4*>(inrow + e);
        float2 w0 = *reinterpret_cast<const float2*>(W + (size_t)(e + 0) * H + h2);
        float2 w1 = *reinterpret_cast<const float2*>(W + (size_t)(e + 1) * H + h2);
        float2 w2 = *reinterpret_cast<const float2*>(W + (size_t)(e + 2) * H + h2);
        float2 w3 = *reinterpret_cast<const float2*>(W + (size_t)(e + 3) * H + h2);
        a0 = fmaf(a4.x, w0.x, a0); a1 = fmaf(a4.x, w0.y, a1);
        a0 = fmaf(a4.y, w1.x, a0); a1 = fmaf(a4.y, w1.y, a1);
        a0 = fmaf(a4.z, w2.x, a0); a1 = fmaf(a4.z, w2.y, a1);
        a0 = fmaf(a4.w, w3.x, a0); a1 = fmaf(a4.w, w3.y, a1);
    }
    float2 r;
    r.x = __builtin_amdgcn_exp2f(a0 * TWO_LOG2E);
    r.y = __builtin_amdgcn_exp2f(a1 * TWO_LOG2E);
    *reinterpret_cast<float2*>(outp + (size_t)row * H + h2) = r;
}

// ---------------------------------------------------------------------------
// Kernel 2: fused scores -> softmax -> PV for QT=8 query rows.
// grid = B * (Q/QT) = 512 blocks, 512 threads, 2 blocks/CU.
// score = sumwv - 2 * sum_h wv[h] * rcp(1 + Eq[h]*Ek[h])
// ---------------------------------------------------------------------------
__global__ __launch_bounds__(512) void attn_fused(
    const float* __restrict__ qp, const float* __restrict__ kp,
    const float* __restrict__ values, const float* __restrict__ wv,
    float* __restrict__ out)
{
    __shared__ float buf[8 * QT * VDIM];      // 64 KB combine buffer
    __shared__ float inv_lds[QT];
    // attn weights (bf16) alias the front 16 KB of buf; overwritten only
    // after the PV loop's __syncthreads().
    unsigned short* attn_bf = reinterpret_cast<unsigned short*>(buf);

    const int tid = (int)threadIdx.x;
    const int b   = (int)blockIdx.x >> 7;
    const int q0  = ((int)blockIdx.x & 127) * QT;
    const float* eqbase = qp + (size_t)(b * QDIM + q0) * H;   // wave-uniform

    float sumwv = 0.f;
    #pragma unroll
    for (int h = 0; h < H; ++h) sumwv += wv[h];
    const float c0 = sumwv * LOG2E;
    const float c1 = 2.0f * LOG2E;

    // ---- phase 1: scores + exp -> bf16 weights in LDS ----
    #pragma unroll
    for (int t = 0; t < 2; ++t) {
        const int kk = t * 512 + tid;
        float kreg[H];
        const float* krow = kp + (size_t)(b * KDIM + kk) * H;
        #pragma unroll
        for (int i = 0; i < H / 4; ++i) {
            float4 v = *reinterpret_cast<const float4*>(krow + i * 4);
            kreg[i * 4 + 0] = v.x; kreg[i * 4 + 1] = v.y;
            kreg[i * 4 + 2] = v.z; kreg[i * 4 + 3] = v.w;
        }
        for (int qr = 0; qr < QT; ++qr) {
            const float* eq = eqbase + qr * H;   // uniform -> scalar loads
            float s2 = 0.f;
            #pragma unroll
            for (int h = 0; h < H; ++h) {
                float u = fmaf(eq[h], kreg[h], 1.0f);
                s2 = fmaf(wv[h], __builtin_amdgcn_rcpf(u), s2);
            }
            float w = __builtin_amdgcn_exp2f(fmaf(-c1, s2, c0));
            unsigned int bits = __float_as_uint(w);
            unsigned short bf = (unsigned short)((bits + 0x7FFFu + ((bits >> 16) & 1u)) >> 16);
            attn_bf[qr * KDIM + kk] = bf;
        }
    }
    __syncthreads();

    // ---- phase 2: softmax denominators ----
    {
        const int row = tid >> 6;          // 0..7
        const int c   = tid & 63;
        float s = 0.f;
        #pragma unroll
        for (int j = 0; j < 16; ++j) {
            unsigned int u = attn_bf[row * KDIM + c + j * 64];
            s += __uint_as_float(u << 16);
        }
        #pragma unroll
        for (int m = 32; m > 0; m >>= 1) s += __shfl_xor(s, m, 64);
        if (c == 0) inv_lds[row] = 1.0f / s;
    }

    // ---- phase 3: PV. thread = (k-partition p of 8, 4 value columns) ----
    const int p  = tid >> 6;
    const int c4 = (tid & 63) * 4;
    float4 acc[QT];
    #pragma unroll
    for (int i = 0; i < QT; ++i) { acc[i].x = 0.f; acc[i].y = 0.f; acc[i].z = 0.f; acc[i].w = 0.f; }

    const float4* vbase = reinterpret_cast<const float4*>(
        values + ((size_t)b * KDIM + p * 128) * VDIM + c4);
    const uint4* attn_u4 = reinterpret_cast<const uint4*>(attn_bf);

    for (int ib = 0; ib < 16; ++ib) {        // 8 keys per iteration
        float4 vv[8];
        #pragma unroll
        for (int j = 0; j < 8; ++j)
            vv[j] = vbase[(size_t)(ib * 8 + j) * (VDIM / 4)];
        #pragma unroll
        for (int qr = 0; qr < QT; ++qr) {
            uint4 aq = attn_u4[(qr * KDIM + p * 128 + ib * 8) >> 3];
            float a;
            a = __uint_as_float(aq.x << 16);
            acc[qr].x = fmaf(a, vv[0].x, acc[qr].x); acc[qr].y = fmaf(a, vv[0].y, acc[qr].y);
            acc[qr].z = fmaf(a, vv[0].z, acc[qr].z); acc[qr].w = fmaf(a, vv[0].w, acc[qr].w);
            a = __uint_as_float(aq.x & 0xFFFF0000u);
            acc[qr].x = fmaf(a, vv[1].x, acc[qr].x); acc[qr].y = fmaf(a, vv[1].y, acc[qr].y);
            acc[qr].z = fmaf(a, vv[1].z, acc[qr].z); acc[qr].w = fmaf(a, vv[1].w, acc[qr].w);
            a = __uint_as_float(aq.y << 16);
            acc[qr].x = fmaf(a, vv[2].x, acc[qr].x); acc[qr].y = fmaf(a, vv[2].y, acc[qr].y);
            acc[qr].z = fmaf(a, vv[2].z, acc[qr].z); acc[qr].w = fmaf(a, vv[2].w, acc[qr].w);
            a = __uint_as_float(aq.y & 0xFFFF0000u);
            acc[qr].x = fmaf(a, vv[3].x, acc[qr].x); acc[qr].y = fmaf(a, vv[3].y, acc[qr].y);
            acc[qr].z = fmaf(a, vv[3].z, acc[qr].z); acc[qr].w = fmaf(a, vv[3].w, acc[qr].w);
            a = __uint_as_float(aq.z << 16);
            acc[qr].x = fmaf(a, vv[4].x, acc[qr].x); acc[qr].y = fmaf(a, vv[4].y, acc[qr].y);
            acc[qr].z = fmaf(a, vv[4].z, acc[qr].z); acc[qr].w = fmaf(a, vv[4].w, acc[qr].w);
            a = __uint_as_float(aq.z & 0xFFFF0000u);
            acc[qr].x = fmaf(a, vv[5].x, acc[qr].x); acc[qr].y = fmaf(a, vv[5].y, acc[qr].y);
            acc[qr].z = fmaf(a, vv[5].z, acc[qr].z); acc[qr].w = fmaf(a, vv[5].w, acc[qr].w);
            a = __uint_as_float(aq.w << 16);
            acc[qr].x = fmaf(a, vv[6].x, acc[qr].x); acc[qr].y = fmaf(a, vv[6].y, acc[qr].y);
            acc[qr].z = fmaf(a, vv[6].z, acc[qr].z); acc[qr].w = fmaf(a, vv[6].w, acc[qr].w);
            a = __uint_as_float(aq.w & 0xFFFF0000u);
            acc[qr].x = fmaf(a, vv[7].x, acc[qr].x); acc[qr].y = fmaf(a, vv[7].y, acc[qr].y);
            acc[qr].z = fmaf(a, vv[7].z, acc[qr].z); acc[qr].w = fmaf(a, vv[7].w, acc[qr].w);
        }
    }
    __syncthreads();   // all attn reads done; buf may now be overwritten

    // ---- single-round combine of the 8 k-partitions ----
    #pragma unroll
    for (int qr = 0; qr < QT; ++qr)
        *reinterpret_cast<float4*>(buf + (p * QT + qr) * VDIM + c4) = acc[qr];
    __syncthreads();

    {
        const int row = tid >> 6;          // 0..7
        const int cc  = (tid & 63) * 4;
        float4 r; r.x = 0.f; r.y = 0.f; r.z = 0.f; r.w = 0.f;
        #pragma unroll
        for (int pp = 0; pp < 8; ++pp) {
            float4 t = *reinterpret_cast<const float4*>(buf + (pp * QT + row) * VDIM + cc);
            r.x += t.x; r.y += t.y; r.z += t.z; r.w += t.w;
        }
        const float s = inv_lds[row];
        r.x *= s; r.y *= s; r.z *= s; r.w *= s;
        *reinterpret_cast<float4*>(out + (size_t)(b * QDIM + q0 + row) * VDIM + cc) = r;
    }
}

extern "C" void kernel_launch(void* const* d_in, const int* in_sizes, int n_in,
                              void* d_out, int out_size, void* d_ws, size_t ws_size,
                              hipStream_t stream) {
    const float* queries = (const float*)d_in[0];
    const float* keys    = (const float*)d_in[1];
    const float* values  = (const float*)d_in[2];
    const float* Wq      = (const float*)d_in[3];
    const float* Wk      = (const float*)d_in[4];
    const float* wv      = (const float*)d_in[5];
    float* out = (float*)d_out;

    float* qp = (float*)d_ws;                       // [4096][32] Eq
    float* kp = qp + (size_t)BATCH * QDIM * H;      // [4096][32] Ek

    hipLaunchKernelGGL(proj_kernel, dim3(256), dim3(512), 0, stream,
                       queries, keys, Wq, Wk, qp, kp);
    hipLaunchKernelGGL(attn_fused, dim3(BATCH * (QDIM / QT)), dim3(512), 0, stream,
                       qp, kp, values, wv, out);
}

// Round 3
// 67.254 us; speedup vs baseline: 1.4745x; 1.4745x over previous
//
#include <hip/hip_runtime.h>

#define BATCH 4
#define QDIM 1024
#define KDIM 1024
#define EDIM 512
#define H 32
#define VDIM 256
#define QT 16

#define TWO_LOG2E 2.8853900817779268f
#define LOG2E 1.4426950408889634f

typedef __attribute__((ext_vector_type(8))) short short8;
typedef __attribute__((ext_vector_type(4))) float f32x4;

static __device__ __forceinline__ unsigned short f32_to_bf16(float f) {
    unsigned int bits = __float_as_uint(f);
    return (unsigned short)((bits + 0x7FFFu + ((bits >> 16) & 1u)) >> 16);
}

// ---------------------------------------------------------------------------
// Kernel 1: Eq = exp2(2*log2e * (queries @ Wq)), Ek likewise.
// Round-1 structure: 256 blocks x 256 thr; 32 rows/block, 8 thr/row, 4 h each.
// ---------------------------------------------------------------------------
__global__ __launch_bounds__(256) void proj_kernel(
    const float* __restrict__ qin, const float* __restrict__ kin,
    const float* __restrict__ Wqm, const float* __restrict__ Wkm,
    float* __restrict__ qp, float* __restrict__ kp)
{
    const int nb = 128;
    const bool is_k = blockIdx.x >= nb;
    const float* in = is_k ? kin : qin;
    const float* W  = is_k ? Wkm : Wqm;
    float* outp     = is_k ? kp : qp;
    const int row = (is_k ? (int)blockIdx.x - nb : (int)blockIdx.x) * 32 + ((int)threadIdx.x >> 3);
    const int h4  = ((int)threadIdx.x & 7) * 4;

    const float* inrow = in + (size_t)row * EDIM;
    float ax = 0.f, ay = 0.f, az = 0.f, aw = 0.f;

    for (int e = 0; e < EDIM; e += 4) {
        float4 a4 = *reinterpret_cast<const float4*>(inrow + e);
        float4 w0 = *reinterpret_cast<const float4*>(W + (size_t)(e + 0) * H + h4);
        float4 w1 = *reinterpret_cast<const float4*>(W + (size_t)(e + 1) * H + h4);
        float4 w2 = *reinterpret_cast<const float4*>(W + (size_t)(e + 2) * H + h4);
        float4 w3 = *reinterpret_cast<const float4*>(W + (size_t)(e + 3) * H + h4);
        ax = fmaf(a4.x, w0.x, ax); ay = fmaf(a4.x, w0.y, ay);
        az = fmaf(a4.x, w0.z, az); aw = fmaf(a4.x, w0.w, aw);
        ax = fmaf(a4.y, w1.x, ax); ay = fmaf(a4.y, w1.y, ay);
        az = fmaf(a4.y, w1.z, az); aw = fmaf(a4.y, w1.w, aw);
        ax = fmaf(a4.z, w2.x, ax); ay = fmaf(a4.z, w2.y, ay);
        az = fmaf(a4.z, w2.z, az); aw = fmaf(a4.z, w2.w, aw);
        ax = fmaf(a4.w, w3.x, ax); ay = fmaf(a4.w, w3.y, ay);
        az = fmaf(a4.w, w3.z, az); aw = fmaf(a4.w, w3.w, aw);
    }
    float4 r;
    r.x = __builtin_amdgcn_exp2f(ax * TWO_LOG2E);
    r.y = __builtin_amdgcn_exp2f(ay * TWO_LOG2E);
    r.z = __builtin_amdgcn_exp2f(az * TWO_LOG2E);
    r.w = __builtin_amdgcn_exp2f(aw * TWO_LOG2E);
    *reinterpret_cast<float4*>(outp + (size_t)row * H + h4) = r;
}

// ---------------------------------------------------------------------------
// Kernel 2: Vt[b][col][k] = bf16(V[b][k][col]). 64x64 tiles via padded LDS.
// grid = 4b x 16kt x 4ct = 256 blocks, 256 threads.
// ---------------------------------------------------------------------------
__global__ __launch_bounds__(256) void vconv_kernel(
    const float* __restrict__ values, unsigned short* __restrict__ vt)
{
    __shared__ float t[64][65];
    const int tid = (int)threadIdx.x;
    const int b  = (int)blockIdx.x & 3;
    const int kt = ((int)blockIdx.x >> 2) & 15;
    const int ct = (int)blockIdx.x >> 6;
    const int k0 = kt * 64, c0 = ct * 64;
    const int col4 = (tid & 15) * 4;
    const int krow = tid >> 4;                    // 0..15

    #pragma unroll
    for (int i = 0; i < 4; ++i) {
        const int kk = i * 16 + krow;
        float4 v = *reinterpret_cast<const float4*>(
            values + ((size_t)(b * KDIM + k0 + kk) * VDIM + c0 + col4));
        t[kk][col4 + 0] = v.x; t[kk][col4 + 1] = v.y;
        t[kk][col4 + 2] = v.z; t[kk][col4 + 3] = v.w;
    }
    __syncthreads();

    const int col = tid >> 2;                     // 0..63
    const int ks  = (tid & 3) * 16;               // 0,16,32,48
    unsigned int pk[8];
    #pragma unroll
    for (int j = 0; j < 8; ++j) {
        unsigned int lo = f32_to_bf16(t[ks + 2 * j][col]);
        unsigned int hi = f32_to_bf16(t[ks + 2 * j + 1][col]);
        pk[j] = lo | (hi << 16);
    }
    unsigned short* dst = vt + ((size_t)(b * VDIM + c0 + col) * KDIM + k0 + ks);
    *reinterpret_cast<uint4*>(dst)     = make_uint4(pk[0], pk[1], pk[2], pk[3]);
    *reinterpret_cast<uint4*>(dst + 8) = make_uint4(pk[4], pk[5], pk[6], pk[7]);
}

// ---------------------------------------------------------------------------
// Kernel 3: fused scores -> softmax -> MFMA PV. QT=16 q rows per block.
// grid = B * (Q/QT) = 256 blocks, 512 threads (8 waves).
// A_lds layout: [kc 0..31][row 0..15][kl 0..31] bf16, byte addr XOR'd with
// ((row&7)<<4) to kill bank conflicts on the MFMA A-fragment ds_read_b128.
// ---------------------------------------------------------------------------
__global__ __launch_bounds__(512) void attn_fused(
    const float* __restrict__ qp, const float* __restrict__ kp,
    const unsigned short* __restrict__ vt, const float* __restrict__ wv,
    float* __restrict__ out)
{
    __shared__ unsigned char a_lds[32 * 1024];
    __shared__ float inv_lds[QT];

    const int tid = (int)threadIdx.x;
    const int b   = (int)blockIdx.x >> 6;
    const int q0  = ((int)blockIdx.x & 63) * QT;
    const float* eqbase = qp + (size_t)(b * QDIM + q0) * H;   // wave-uniform

    float sumwv = 0.f;
    #pragma unroll
    for (int h = 0; h < H; ++h) sumwv += wv[h];
    const float c0 = sumwv * LOG2E;
    const float c1 = 2.0f * LOG2E;

    // ---- phase 1: scores -> exp -> bf16 weights into swizzled A_lds ----
    #pragma unroll
    for (int t = 0; t < 2; ++t) {
        const int kk   = t * 512 + tid;
        const int base = (kk >> 5) * 1024 + (kk & 31) * 2;
        float kreg[H];
        const float* krow = kp + (size_t)(b * KDIM + kk) * H;
        #pragma unroll
        for (int i = 0; i < H / 4; ++i) {
            float4 v = *reinterpret_cast<const float4*>(krow + i * 4);
            kreg[i * 4 + 0] = v.x; kreg[i * 4 + 1] = v.y;
            kreg[i * 4 + 2] = v.z; kreg[i * 4 + 3] = v.w;
        }
        for (int qr = 0; qr < QT; ++qr) {
            const float* eq = eqbase + qr * H;    // uniform -> s_loads
            float s2 = 0.f;
            #pragma unroll
            for (int h = 0; h < H; ++h) {
                float u = fmaf(eq[h], kreg[h], 1.0f);
                s2 = fmaf(wv[h], __builtin_amdgcn_rcpf(u), s2);
            }
            float wgt = __builtin_amdgcn_exp2f(fmaf(-c1, s2, c0));
            const int addr = (base + qr * 64) ^ ((qr & 7) << 4);
            *reinterpret_cast<unsigned short*>(a_lds + addr) = f32_to_bf16(wgt);
        }
    }
    __syncthreads();

    // ---- phase 2: softmax denominators (32 lanes per q row) ----
    {
        const int row = tid >> 5;                 // 0..15
        const int c   = tid & 31;
        float s = 0.f;
        #pragma unroll
        for (int j = 0; j < 32; ++j) {
            const int addr = (j * 1024 + row * 64 + c * 2) ^ ((row & 7) << 4);
            unsigned int u = *reinterpret_cast<const unsigned short*>(a_lds + addr);
            s += __uint_as_float(u << 16);
        }
        #pragma unroll
        for (int m = 16; m > 0; m >>= 1) s += __shfl_xor(s, m, 64);
        if (c == 0) inv_lds[row] = 1.0f / s;
    }
    __syncthreads();

    // ---- phase 3: PV via MFMA. wave w owns 32 V-columns. ----
    const int w    = tid >> 6;                    // 0..7
    const int lane = tid & 63;
    const int colb = w * 32;
    const int arow = lane & 15;                   // A row / B col / D col
    const int aq   = lane >> 4;                   // 0..3 (k-quad)
    f32x4 acc0 = {0.f, 0.f, 0.f, 0.f};
    f32x4 acc1 = {0.f, 0.f, 0.f, 0.f};

    const unsigned short* vt_b = vt + (size_t)b * VDIM * KDIM;
    const unsigned short* vtc0 = vt_b + (size_t)(colb + arow) * KDIM;
    const unsigned short* vtc1 = vt_b + (size_t)(colb + 16 + arow) * KDIM;

    for (int half = 0; half < 2; ++half) {
        short8 afrag[16];
        #pragma unroll
        for (int kc = 0; kc < 16; ++kc) {
            const int addr = ((half * 16 + kc) * 1024 + arow * 64 + aq * 16)
                             ^ ((arow & 7) << 4);
            afrag[kc] = *reinterpret_cast<const short8*>(a_lds + addr);
        }
        #pragma unroll
        for (int kc = 0; kc < 16; ++kc) {
            const int k = half * 512 + kc * 32 + aq * 8;
            short8 b0 = *reinterpret_cast<const short8*>(vtc0 + k);
            short8 b1 = *reinterpret_cast<const short8*>(vtc1 + k);
            acc0 = __builtin_amdgcn_mfma_f32_16x16x32_bf16(afrag[kc], b0, acc0, 0, 0, 0);
            acc1 = __builtin_amdgcn_mfma_f32_16x16x32_bf16(afrag[kc], b1, acc1, 0, 0, 0);
        }
    }

    // ---- epilogue: scale by 1/denominator, store fp32 ----
    #pragma unroll
    for (int r = 0; r < 4; ++r) {
        const int row = aq * 4 + r;               // C/D: row=(lane>>4)*4+reg
        const float inv = inv_lds[row];
        float* orow = out + (size_t)(b * QDIM + q0 + row) * VDIM + colb;
        orow[arow]      = acc0[r] * inv;
        orow[16 + arow] = acc1[r] * inv;
    }
}

extern "C" void kernel_launch(void* const* d_in, const int* in_sizes, int n_in,
                              void* d_out, int out_size, void* d_ws, size_t ws_size,
                              hipStream_t stream) {
    const float* queries = (const float*)d_in[0];
    const float* keys    = (const float*)d_in[1];
    const float* values  = (const float*)d_in[2];
    const float* Wq      = (const float*)d_in[3];
    const float* Wk      = (const float*)d_in[4];
    const float* wv      = (const float*)d_in[5];
    float* out = (float*)d_out;

    float* qp = (float*)d_ws;                            // [4096][32] f32
    float* kp = qp + (size_t)BATCH * QDIM * H;           // [4096][32] f32
    unsigned short* vt = (unsigned short*)(kp + (size_t)BATCH * KDIM * H); // [4][256][1024] bf16

    hipLaunchKernelGGL(vconv_kernel, dim3(256), dim3(256), 0, stream, values, vt);
    hipLaunchKernelGGL(proj_kernel, dim3(256), dim3(256), 0, stream,
                       queries, keys, Wq, Wk, qp, kp);
    hipLaunchKernelGGL(attn_fused, dim3(BATCH * (QDIM / QT)), dim3(512), 0, stream,
                       qp, kp, vt, wv, out);
}

// Round 4
// 61.231 us; speedup vs baseline: 1.6196x; 1.0984x over previous
//
#include <hip/hip_runtime.h>

#define BATCH 4
#define QDIM 1024
#define KDIM 1024
#define EDIM 512
#define H 32
#define VDIM 256
#define QT 16

#define TWO_LOG2E 2.8853900817779268f
#define LOG2E 1.4426950408889634f

typedef __attribute__((ext_vector_type(8))) short short8;
typedef __attribute__((ext_vector_type(4))) float f32x4;

static __device__ __forceinline__ unsigned short f32_to_bf16(float f) {
    unsigned int bits = __float_as_uint(f);
    return (unsigned short)((bits + 0x7FFFu + ((bits >> 16) & 1u)) >> 16);
}

// ---------------------------------------------------------------------------
// Prep kernel: blocks 0..255 = projections (Eq/Ek), blocks 256..511 = V
// transpose+bf16. Merged so both co-resident (2 blocks/CU) and latency of
// each hides under the other.
// ---------------------------------------------------------------------------
__global__ __launch_bounds__(256) void prep_kernel(
    const float* __restrict__ qin, const float* __restrict__ kin,
    const float* __restrict__ Wqm, const float* __restrict__ Wkm,
    const float* __restrict__ values,
    float* __restrict__ qp, float* __restrict__ kp,
    unsigned short* __restrict__ vt)
{
    __shared__ float t[64][65];
    const int tid = (int)threadIdx.x;
    const int bid = (int)blockIdx.x;

    if (bid < 256) {
        // ---- projection: Eq = exp2(2*log2e * (row @ W)) ----
        const bool is_k = bid >= 128;
        const float* in = is_k ? kin : qin;
        const float* W  = is_k ? Wkm : Wqm;
        float* outp     = is_k ? kp : qp;
        const int row = (bid & 127) * 32 + (tid >> 3);
        const int h4  = (tid & 7) * 4;

        const float* inrow = in + (size_t)row * EDIM;
        float ax = 0.f, ay = 0.f, az = 0.f, aw = 0.f;

        for (int e = 0; e < EDIM; e += 4) {
            float4 a4 = *reinterpret_cast<const float4*>(inrow + e);
            float4 w0 = *reinterpret_cast<const float4*>(W + (size_t)(e + 0) * H + h4);
            float4 w1 = *reinterpret_cast<const float4*>(W + (size_t)(e + 1) * H + h4);
            float4 w2 = *reinterpret_cast<const float4*>(W + (size_t)(e + 2) * H + h4);
            float4 w3 = *reinterpret_cast<const float4*>(W + (size_t)(e + 3) * H + h4);
            ax = fmaf(a4.x, w0.x, ax); ay = fmaf(a4.x, w0.y, ay);
            az = fmaf(a4.x, w0.z, az); aw = fmaf(a4.x, w0.w, aw);
            ax = fmaf(a4.y, w1.x, ax); ay = fmaf(a4.y, w1.y, ay);
            az = fmaf(a4.y, w1.z, az); aw = fmaf(a4.y, w1.w, aw);
            ax = fmaf(a4.z, w2.x, ax); ay = fmaf(a4.z, w2.y, ay);
            az = fmaf(a4.z, w2.z, az); aw = fmaf(a4.z, w2.w, aw);
            ax = fmaf(a4.w, w3.x, ax); ay = fmaf(a4.w, w3.y, ay);
            az = fmaf(a4.w, w3.z, az); aw = fmaf(a4.w, w3.w, aw);
        }
        float4 r;
        r.x = __builtin_amdgcn_exp2f(ax * TWO_LOG2E);
        r.y = __builtin_amdgcn_exp2f(ay * TWO_LOG2E);
        r.z = __builtin_amdgcn_exp2f(az * TWO_LOG2E);
        r.w = __builtin_amdgcn_exp2f(aw * TWO_LOG2E);
        *reinterpret_cast<float4*>(outp + (size_t)row * H + h4) = r;
    } else {
        // ---- V transpose to bf16: Vt[b][col][k] ----
        const int vb = bid - 256;
        const int b  = vb & 3;
        const int kt = (vb >> 2) & 15;
        const int ct = vb >> 6;
        const int k0 = kt * 64, c0 = ct * 64;
        const int col4 = (tid & 15) * 4;
        const int krow = tid >> 4;

        #pragma unroll
        for (int i = 0; i < 4; ++i) {
            const int kk = i * 16 + krow;
            float4 v = *reinterpret_cast<const float4*>(
                values + ((size_t)(b * KDIM + k0 + kk) * VDIM + c0 + col4));
            t[kk][col4 + 0] = v.x; t[kk][col4 + 1] = v.y;
            t[kk][col4 + 2] = v.z; t[kk][col4 + 3] = v.w;
        }
        __syncthreads();

        const int col = tid >> 2;
        const int ks  = (tid & 3) * 16;
        unsigned int pk[8];
        #pragma unroll
        for (int j = 0; j < 8; ++j) {
            unsigned int lo = f32_to_bf16(t[ks + 2 * j][col]);
            unsigned int hi = f32_to_bf16(t[ks + 2 * j + 1][col]);
            pk[j] = lo | (hi << 16);
        }
        unsigned short* dst = vt + ((size_t)(b * VDIM + c0 + col) * KDIM + k0 + ks);
        *reinterpret_cast<uint4*>(dst)     = make_uint4(pk[0], pk[1], pk[2], pk[3]);
        *reinterpret_cast<uint4*>(dst + 8) = make_uint4(pk[4], pk[5], pk[6], pk[7]);
    }
}

// ---------------------------------------------------------------------------
// Fused scores -> softmax -> MFMA PV. QT=16 q rows per block.
// grid = 256 blocks x 1024 threads (16 waves, 4 waves/SIMD, 1 block/CU).
// A_lds: [kc 0..31][row 0..15][kl 0..31] bf16, byte addr ^ ((row&7)<<4).
// ---------------------------------------------------------------------------
__global__ __launch_bounds__(1024, 4) void attn_fused(
    const float* __restrict__ qp, const float* __restrict__ kp,
    const unsigned short* __restrict__ vt, const float* __restrict__ wv,
    float* __restrict__ out)
{
    __shared__ unsigned char a_lds[32 * 1024];
    __shared__ float inv_lds[QT];

    const int tid = (int)threadIdx.x;
    const int b   = (int)blockIdx.x >> 6;
    const int q0  = ((int)blockIdx.x & 63) * QT;
    const float* eqbase = qp + (size_t)(b * QDIM + q0) * H;   // wave-uniform

    float sumwv = 0.f;
    #pragma unroll
    for (int h = 0; h < H; ++h) sumwv += wv[h];
    const float c0 = sumwv * LOG2E;
    const float c1 = 2.0f * LOG2E;

    // ---- phase 1: one k-row per thread, 16 q rows each ----
    {
        const int kk   = tid;
        const int base = (kk >> 5) * 1024 + (kk & 31) * 2;
        float kreg[H];
        const float* krow = kp + (size_t)(b * KDIM + kk) * H;
        #pragma unroll
        for (int i = 0; i < H / 4; ++i) {
            float4 v = *reinterpret_cast<const float4*>(krow + i * 4);
            kreg[i * 4 + 0] = v.x; kreg[i * 4 + 1] = v.y;
            kreg[i * 4 + 2] = v.z; kreg[i * 4 + 3] = v.w;
        }
        for (int qr = 0; qr < QT; ++qr) {
            const float* eq = eqbase + qr * H;    // uniform -> s_loads
            float s2a = 0.f, s2b = 0.f;
            #pragma unroll
            for (int hh = 0; hh < H / 2; ++hh) {
                float u0 = fmaf(eq[2 * hh], kreg[2 * hh], 1.0f);
                s2a = fmaf(wv[2 * hh], __builtin_amdgcn_rcpf(u0), s2a);
                float u1 = fmaf(eq[2 * hh + 1], kreg[2 * hh + 1], 1.0f);
                s2b = fmaf(wv[2 * hh + 1], __builtin_amdgcn_rcpf(u1), s2b);
            }
            float wgt = __builtin_amdgcn_exp2f(fmaf(-c1, s2a + s2b, c0));
            const int addr = (base + qr * 64) ^ ((qr & 7) << 4);
            *reinterpret_cast<unsigned short*>(a_lds + addr) = f32_to_bf16(wgt);
        }
    }
    __syncthreads();

    // ---- phase 2: softmax denominator, one wave per q row ----
    {
        const int row = tid >> 6;                 // 0..15
        const int c   = tid & 63;
        float s = 0.f;
        #pragma unroll
        for (int j = 0; j < 16; ++j) {
            const int k = c + j * 64;
            const int addr = ((k >> 5) * 1024 + row * 64 + (k & 31) * 2)
                             ^ ((row & 7) << 4);
            unsigned int u = *reinterpret_cast<const unsigned short*>(a_lds + addr);
            s += __uint_as_float(u << 16);
        }
        #pragma unroll
        for (int m = 32; m > 0; m >>= 1) s += __shfl_xor(s, m, 64);
        if (c == 0) inv_lds[row] = 1.0f / s;
    }
    __syncthreads();

    // ---- phase 3: MFMA PV. wave w owns 16 V-columns. ----
    const int w    = tid >> 6;                    // 0..15
    const int lane = tid & 63;
    const int colb = w * 16;
    const int arow = lane & 15;                   // A row / B col / D col
    const int aq   = lane >> 4;                   // k-quad
    f32x4 acc = {0.f, 0.f, 0.f, 0.f};

    const unsigned short* vtc = vt + ((size_t)b * VDIM + colb + arow) * KDIM;

    for (int kc0 = 0; kc0 < 32; kc0 += 8) {
        #pragma unroll
        for (int kc = 0; kc < 8; ++kc) {
            const int kci = kc0 + kc;
            const int addr = (kci * 1024 + arow * 64 + aq * 16) ^ ((arow & 7) << 4);
            short8 af = *reinterpret_cast<const short8*>(a_lds + addr);
            short8 bv = *reinterpret_cast<const short8*>(vtc + kci * 32 + aq * 8);
            acc = __builtin_amdgcn_mfma_f32_16x16x32_bf16(af, bv, acc, 0, 0, 0);
        }
    }

    // ---- epilogue ----
    #pragma unroll
    for (int r = 0; r < 4; ++r) {
        const int row = aq * 4 + r;               // C/D: row=(lane>>4)*4+reg
        out[(size_t)(b * QDIM + q0 + row) * VDIM + colb + arow] = acc[r] * inv_lds[row];
    }
}

extern "C" void kernel_launch(void* const* d_in, const int* in_sizes, int n_in,
                              void* d_out, int out_size, void* d_ws, size_t ws_size,
                              hipStream_t stream) {
    const float* queries = (const float*)d_in[0];
    const float* keys    = (const float*)d_in[1];
    const float* values  = (const float*)d_in[2];
    const float* Wq      = (const float*)d_in[3];
    const float* Wk      = (const float*)d_in[4];
    const float* wv      = (const float*)d_in[5];
    float* out = (float*)d_out;

    float* qp = (float*)d_ws;                            // [4096][32] f32 Eq
    float* kp = qp + (size_t)BATCH * QDIM * H;           // [4096][32] f32 Ek
    unsigned short* vt = (unsigned short*)(kp + (size_t)BATCH * KDIM * H); // [4][256][1024] bf16

    hipLaunchKernelGGL(prep_kernel, dim3(512), dim3(256), 0, stream,
                       queries, keys, Wq, Wk, values, qp, kp, vt);
    hipLaunchKernelGGL(attn_fused, dim3(BATCH * (QDIM / QT)), dim3(1024), 0, stream,
                       qp, kp, vt, wv, out);
}